// Round 1
// baseline (222.959 us; speedup 1.0000x reference)
//
#include <hip/hip_runtime.h>

#define EPS 1e-5f

typedef __bf16 bf16x8 __attribute__((ext_vector_type(8)));
typedef unsigned short ushort8 __attribute__((ext_vector_type(8)));
typedef float f32x4 __attribute__((ext_vector_type(4)));

static __device__ __forceinline__ unsigned short f2bf(float f) {
  unsigned int u = __float_as_uint(f);
  u += 0x7fffu + ((u >> 16) & 1u);
  return (unsigned short)(u >> 16);
}

// ---------------- ws layout (bytes) ----------------
// h2  (bf16, NHWC [128][1024][128]) : [0, 33554432)
// w1b (bf16, [128 oc][512 c], bn2-scale folded): 33554432 .. +131072
// w2b (bf16, [32 oc][9 tap][128 c]): 33685504 .. +73728
// s1  (f32 [512]): 33759232
// b1  (f32 [512]): 33761280
// bias2 (f32 [128]): 33763328

// ---------------- kernel 0: prep folded weights ----------------
__global__ void prep_kernel(const float* __restrict__ w1,
                            const float* __restrict__ gamma2,
                            const float* __restrict__ beta2,
                            const float* __restrict__ mean2,
                            const float* __restrict__ var2,
                            const float* __restrict__ w2,
                            unsigned short* __restrict__ w1b,
                            unsigned short* __restrict__ w2b,
                            float* __restrict__ bias2) {
  int idx = blockIdx.x * 256 + threadIdx.x;
  if (idx < 128 * 512) {
    int oc = idx >> 9;
    float s2 = gamma2[oc] * rsqrtf(var2[oc] + EPS);
    w1b[idx] = f2bf(w1[idx] * s2);
  } else if (idx < 128 * 512 + 32 * 1152) {
    int i2 = idx - 128 * 512;
    int oc = i2 / 1152;
    int rem = i2 - oc * 1152;
    int tap = rem >> 7;     // dy*3+dx
    int c = rem & 127;
    // w2 is OIHW (32,128,3,3) -> w2b[oc][tap][c]
    w2b[i2] = f2bf(w2[(oc * 128 + c) * 9 + tap]);
  } else if (idx < 128 * 512 + 32 * 1152 + 128) {
    int oc = idx - (128 * 512 + 32 * 1152);
    float s2 = gamma2[oc] * rsqrtf(var2[oc] + EPS);
    bias2[oc] = beta2[oc] - mean2[oc] * s2;
  }
}

// ---------------- kernel 1: bn1 batch stats + concat-copy of x ----------------
// one block per channel c; reduces 128*1024 elements, also copies x -> out[:, c]
__global__ void __launch_bounds__(256) stats_copy_kernel(
    const float* __restrict__ x, const float* __restrict__ g1,
    const float* __restrict__ be1, float* __restrict__ out,
    float* __restrict__ s1, float* __restrict__ b1) {
  const int c = blockIdx.x;
  const int t = threadIdx.x;
  float sum = 0.f, sq = 0.f;
  const float4* __restrict__ x4 = (const float4*)x;
  float4* out4 = (float4*)out;
  for (int n = 0; n < 128; ++n) {
    float4 v = x4[(((size_t)n * 512 + c) << 8) + t];  // 1024 floats = 256 f4
    out4[(((size_t)n * 544 + c) << 8) + t] = v;
    sum += v.x + v.y + v.z + v.w;
    sq += v.x * v.x + v.y * v.y + v.z * v.z + v.w * v.w;
  }
  __shared__ float ls[2][4];
  for (int off = 32; off > 0; off >>= 1) {
    sum += __shfl_down(sum, off);
    sq += __shfl_down(sq, off);
  }
  int w = t >> 6;
  if ((t & 63) == 0) { ls[0][w] = sum; ls[1][w] = sq; }
  __syncthreads();
  if (t == 0) {
    float S = ls[0][0] + ls[0][1] + ls[0][2] + ls[0][3];
    float Q = ls[1][0] + ls[1][1] + ls[1][2] + ls[1][3];
    float mean = S * (1.0f / 131072.0f);
    float var = Q * (1.0f / 131072.0f) - mean * mean;
    float s = g1[c] * rsqrtf(var + EPS);
    s1[c] = s;
    b1[c] = be1[c] - mean * s;
  }
}

// ---------------- kernel 2: bn1+relu -> 1x1 conv -> bn2+relu -> h2 (bf16 NHWC) ----
// grid: 512 blocks (128 n * 4 quarters), 256 thr = 4 waves, wave = 128 oc x 64 px
__global__ void __launch_bounds__(256, 2) conv1_kernel(
    const float* __restrict__ x, const unsigned short* __restrict__ w1b,
    const float* __restrict__ s1, const float* __restrict__ b1,
    const float* __restrict__ bias2, unsigned short* __restrict__ h2) {
  const int t = threadIdx.x;
  const int lane = t & 63;
  const int wv = t >> 6;
  const int n = blockIdx.x >> 2;
  const int p0w = (blockIdx.x & 3) * 256 + wv * 64;
  const int l15 = lane & 15;
  const int kb = lane >> 4;  // 0..3

  f32x4 acc[8][4];
#pragma unroll
  for (int m = 0; m < 8; ++m)
#pragma unroll
    for (int g = 0; g < 4; ++g) acc[m][g] = (f32x4){0.f, 0.f, 0.f, 0.f};

  const float* __restrict__ xn = x + (size_t)n * 512 * 1024;

  for (int c0 = 0; c0 < 512; c0 += 32) {
    const int cbase = c0 + kb * 8;
    float s1v[8], b1v[8];
#pragma unroll
    for (int j = 0; j < 8; ++j) {
      s1v[j] = s1[cbase + j];
      b1v[j] = b1[cbase + j];
    }
    bf16x8 bf[4];
#pragma unroll
    for (int g = 0; g < 4; ++g) {
      const int p = p0w + g * 16 + l15;
      ushort8 tmp;
#pragma unroll
      for (int j = 0; j < 8; ++j) {
        float xv = xn[(size_t)(cbase + j) * 1024 + p];
        float a = fmaxf(fmaf(xv, s1v[j], b1v[j]), 0.f);
        tmp[j] = f2bf(a);
      }
      bf[g] = __builtin_bit_cast(bf16x8, tmp);
    }
#pragma unroll
    for (int m = 0; m < 8; ++m) {
      bf16x8 af = *(const bf16x8*)(w1b + (size_t)(m * 16 + l15) * 512 + cbase);
#pragma unroll
      for (int g = 0; g < 4; ++g)
        acc[m][g] = __builtin_amdgcn_mfma_f32_16x16x32_bf16(af, bf[g], acc[m][g], 0, 0, 0);
    }
  }

  // epilogue: h2[n][p][oc] = relu(acc + bias2)
#pragma unroll
  for (int m = 0; m < 8; ++m) {
    const int ocb = m * 16 + kb * 4;  // D row = kb*4 + r
    float bz0 = bias2[ocb + 0], bz1 = bias2[ocb + 1];
    float bz2 = bias2[ocb + 2], bz3 = bias2[ocb + 3];
#pragma unroll
    for (int g = 0; g < 4; ++g) {
      const int p = p0w + g * 16 + l15;
      ushort4 hv;
      hv.x = f2bf(fmaxf(acc[m][g][0] + bz0, 0.f));
      hv.y = f2bf(fmaxf(acc[m][g][1] + bz1, 0.f));
      hv.z = f2bf(fmaxf(acc[m][g][2] + bz2, 0.f));
      hv.w = f2bf(fmaxf(acc[m][g][3] + bz3, 0.f));
      *(ushort4*)(h2 + ((size_t)n * 1024 + p) * 128 + ocb) = hv;
    }
  }
}

// ---------------- kernel 3: 3x3 conv (pad 1) h2 -> out[:, 512:544] ----------------
// grid: 512 blocks, 4 waves, wave = 32 oc x 64 px
__global__ void __launch_bounds__(256) conv2_kernel(
    const unsigned short* __restrict__ h2, const unsigned short* __restrict__ w2b,
    float* __restrict__ out) {
  const int t = threadIdx.x;
  const int lane = t & 63;
  const int wv = t >> 6;
  const int n = blockIdx.x >> 2;
  const int pbase = (blockIdx.x & 3) * 256 + wv * 64;
  const int l15 = lane & 15;
  const int kb = lane >> 4;

  f32x4 acc[2][4];
#pragma unroll
  for (int m = 0; m < 2; ++m)
#pragma unroll
    for (int g = 0; g < 4; ++g) acc[m][g] = (f32x4){0.f, 0.f, 0.f, 0.f};

  const unsigned short* __restrict__ h2n = h2 + (size_t)n * 1024 * 128;

#pragma unroll
  for (int tap = 0; tap < 9; ++tap) {
    const int dy = tap / 3 - 1;
    const int dx = tap % 3 - 1;
#pragma unroll
    for (int c0 = 0; c0 < 128; c0 += 32) {
      const int cb = c0 + kb * 8;
      bf16x8 af[2];
#pragma unroll
      for (int m = 0; m < 2; ++m)
        af[m] = *(const bf16x8*)(w2b + (size_t)(m * 16 + l15) * 1152 + tap * 128 + cb);
#pragma unroll
      for (int g = 0; g < 4; ++g) {
        const int p = pbase + g * 16 + l15;
        const int y = (p >> 5) & 31;
        const int xx = p & 31;
        const int y2 = y + dy;
        const int x2 = xx + dx;
        bf16x8 bv = __builtin_bit_cast(bf16x8, (ushort8){0, 0, 0, 0, 0, 0, 0, 0});
        if (y2 >= 0 && y2 < 32 && x2 >= 0 && x2 < 32)
          bv = *(const bf16x8*)(h2n + ((size_t)(y2 * 32 + x2)) * 128 + cb);
#pragma unroll
        for (int m = 0; m < 2; ++m)
          acc[m][g] = __builtin_amdgcn_mfma_f32_16x16x32_bf16(af[m], bv, acc[m][g], 0, 0, 0);
      }
    }
  }

#pragma unroll
  for (int m = 0; m < 2; ++m) {
    const int oc = m * 16 + kb * 4;
#pragma unroll
    for (int g = 0; g < 4; ++g) {
      const int p = pbase + g * 16 + l15;
#pragma unroll
      for (int r = 0; r < 4; ++r)
        out[((size_t)n * 544 + 512 + oc + r) * 1024 + p] = acc[m][g][r];
    }
  }
}

extern "C" void kernel_launch(void* const* d_in, const int* in_sizes, int n_in,
                              void* d_out, int out_size, void* d_ws, size_t ws_size,
                              hipStream_t stream) {
  const float* x = (const float*)d_in[0];
  const float* gamma1 = (const float*)d_in[1];
  const float* beta1 = (const float*)d_in[2];
  const float* w1 = (const float*)d_in[3];
  const float* gamma2 = (const float*)d_in[4];
  const float* beta2 = (const float*)d_in[5];
  const float* mean2 = (const float*)d_in[6];
  const float* var2 = (const float*)d_in[7];
  const float* w2 = (const float*)d_in[8];
  float* out = (float*)d_out;

  char* ws = (char*)d_ws;
  unsigned short* h2 = (unsigned short*)ws;
  unsigned short* w1b = (unsigned short*)(ws + 33554432);
  unsigned short* w2b = (unsigned short*)(ws + 33685504);
  float* s1 = (float*)(ws + 33759232);
  float* b1 = (float*)(ws + 33761280);
  float* bias2 = (float*)(ws + 33763328);

  prep_kernel<<<401, 256, 0, stream>>>(w1, gamma2, beta2, mean2, var2, w2, w1b, w2b, bias2);
  stats_copy_kernel<<<512, 256, 0, stream>>>(x, gamma1, beta1, out, s1, b1);
  conv1_kernel<<<512, 256, 0, stream>>>(x, w1b, s1, b1, bias2, h2);
  conv2_kernel<<<512, 256, 0, stream>>>(h2, w2b, out);
}

// Round 3
// 207.157 us; speedup vs baseline: 1.0763x; 1.0763x over previous
//
#include <hip/hip_runtime.h>

#define EPS 1e-5f

typedef __bf16 bf16x8 __attribute__((ext_vector_type(8)));
typedef __bf16 bf16x4 __attribute__((ext_vector_type(4)));
typedef unsigned short ushort8 __attribute__((ext_vector_type(8)));
typedef float f32x4 __attribute__((ext_vector_type(4)));

static __device__ __forceinline__ unsigned short f2bf(float f) {
  unsigned int u = __float_as_uint(f);
  u += 0x7fffu + ((u >> 16) & 1u);
  return (unsigned short)(u >> 16);
}

// ---------------- ws layout (bytes) ----------------
// h2   (bf16, NHWC [128][1024][128])               : 0 .. 33554432
// w1b  (bf16, [128 oc][512 c], bn2-scale folded)   : 33554432 .. +131072
// w2b  (bf16, [32 oc][9 tap][128 c])               : 33685504 .. +73728
// s1   (f32 [512])                                 : 33759232
// b1   (f32 [512])                                 : 33761280
// bias2(f32 [128])                                 : 33763328
// psum (f32 [512*8])                               : 33763840
// psq  (f32 [512*8])                               : 33780224

// ---------------- kernel 0: prep folded weights ----------------
__global__ void prep_kernel(const float* __restrict__ w1,
                            const float* __restrict__ gamma2,
                            const float* __restrict__ beta2,
                            const float* __restrict__ mean2,
                            const float* __restrict__ var2,
                            const float* __restrict__ w2,
                            unsigned short* __restrict__ w1b,
                            unsigned short* __restrict__ w2b,
                            float* __restrict__ bias2) {
  int idx = blockIdx.x * 256 + threadIdx.x;
  if (idx < 128 * 512) {
    int oc = idx >> 9;
    float s2 = gamma2[oc] * rsqrtf(var2[oc] + EPS);
    w1b[idx] = f2bf(w1[idx] * s2);
  } else if (idx < 128 * 512 + 32 * 1152) {
    int i2 = idx - 128 * 512;
    int oc = i2 / 1152;
    int rem = i2 - oc * 1152;
    int tap = rem >> 7;     // dy*3+dx
    int c = rem & 127;
    // w2 is OIHW (32,128,3,3) -> w2b[oc][tap][c]
    w2b[i2] = f2bf(w2[(oc * 128 + c) * 9 + tap]);
  } else if (idx < 128 * 512 + 32 * 1152 + 128) {
    int oc = idx - (128 * 512 + 32 * 1152);
    float s2 = gamma2[oc] * rsqrtf(var2[oc] + EPS);
    bias2[oc] = beta2[oc] - mean2[oc] * s2;
  }
}

// ---------------- kernel 1: bn1 partial stats + concat-copy of x ----------------
// grid 4096: block = nq*512 + c  (nq-major so n=112..127 is touched LAST -> freshest in L3)
// copy writes are nontemporal so the x read-stream owns L3.
__global__ void __launch_bounds__(256) stats_copy_kernel(
    const float* __restrict__ x, float* __restrict__ out,
    float* __restrict__ psum, float* __restrict__ psq) {
  const int c = blockIdx.x & 511;
  const int nq = blockIdx.x >> 9;
  const int t = threadIdx.x;
  float sum = 0.f, sq = 0.f;
  const f32x4* __restrict__ x4 = (const f32x4*)x;
  f32x4* out4 = (f32x4*)out;
#pragma unroll 4
  for (int i = 0; i < 16; ++i) {
    const int n = nq * 16 + i;
    f32x4 v = x4[(((size_t)n * 512 + c) << 8) + t];
    __builtin_nontemporal_store(v, &out4[(((size_t)n * 544 + c) << 8) + t]);
    sum += v[0] + v[1] + v[2] + v[3];
    sq += v[0] * v[0] + v[1] * v[1] + v[2] * v[2] + v[3] * v[3];
  }
  __shared__ float ls[2][4];
  for (int off = 32; off > 0; off >>= 1) {
    sum += __shfl_down(sum, off);
    sq += __shfl_down(sq, off);
  }
  const int w = t >> 6;
  if ((t & 63) == 0) { ls[0][w] = sum; ls[1][w] = sq; }
  __syncthreads();
  if (t == 0) {
    psum[c * 8 + nq] = ls[0][0] + ls[0][1] + ls[0][2] + ls[0][3];
    psq[c * 8 + nq] = ls[1][0] + ls[1][1] + ls[1][2] + ls[1][3];
  }
}

// ---------------- kernel 1b: finalize bn1 scale/shift (deterministic) ----------------
__global__ void reduce_kernel(const float* __restrict__ psum,
                              const float* __restrict__ psq,
                              const float* __restrict__ g1,
                              const float* __restrict__ be1,
                              float* __restrict__ s1, float* __restrict__ b1) {
  int c = blockIdx.x * 256 + threadIdx.x;
  if (c < 512) {
    float S = 0.f, Q = 0.f;
#pragma unroll
    for (int q = 0; q < 8; ++q) { S += psum[c * 8 + q]; Q += psq[c * 8 + q]; }
    float mean = S * (1.0f / 131072.0f);
    float var = Q * (1.0f / 131072.0f) - mean * mean;
    float s = g1[c] * rsqrtf(var + EPS);
    s1[c] = s;
    b1[c] = be1[c] - mean * s;
  }
}

// ---------------- kernel 2: bn1+relu -> 1x1 conv -> bn2+relu -> h2 (bf16 NHWC) ----
// grid: 512 blocks (128 n * 4 quarters), 256 thr = 4 waves, wave = 128 oc x 64 px
// n DESCENDING so we first consume the x lines stats touched last (L3 recency).
__global__ void __launch_bounds__(256, 2) conv1_kernel(
    const float* __restrict__ x, const unsigned short* __restrict__ w1b,
    const float* __restrict__ s1, const float* __restrict__ b1,
    const float* __restrict__ bias2, unsigned short* __restrict__ h2) {
  const int t = threadIdx.x;
  const int lane = t & 63;
  const int wv = t >> 6;
  const int n = 127 - (blockIdx.x >> 2);
  const int p0w = (blockIdx.x & 3) * 256 + wv * 64;
  const int l15 = lane & 15;
  const int kb = lane >> 4;  // 0..3

  f32x4 acc[8][4];
#pragma unroll
  for (int m = 0; m < 8; ++m)
#pragma unroll
    for (int g = 0; g < 4; ++g) acc[m][g] = (f32x4){0.f, 0.f, 0.f, 0.f};

  const float* __restrict__ xn = x + (size_t)n * 512 * 1024;

  for (int c0 = 0; c0 < 512; c0 += 32) {
    const int cbase = c0 + kb * 8;
    float s1v[8], b1v[8];
#pragma unroll
    for (int j = 0; j < 8; ++j) {
      s1v[j] = s1[cbase + j];
      b1v[j] = b1[cbase + j];
    }
    bf16x8 bf[4];
#pragma unroll
    for (int g = 0; g < 4; ++g) {
      const int p = p0w + g * 16 + l15;
      bf16x8 tmp;
#pragma unroll
      for (int j = 0; j < 8; ++j) {
        float xv = xn[(size_t)(cbase + j) * 1024 + p];
        float a = fmaxf(fmaf(xv, s1v[j], b1v[j]), 0.f);
        tmp[j] = (__bf16)a;
      }
      bf[g] = tmp;
    }
#pragma unroll
    for (int m = 0; m < 8; ++m) {
      bf16x8 af = *(const bf16x8*)(w1b + (size_t)(m * 16 + l15) * 512 + cbase);
#pragma unroll
      for (int g = 0; g < 4; ++g)
        acc[m][g] = __builtin_amdgcn_mfma_f32_16x16x32_bf16(af, bf[g], acc[m][g], 0, 0, 0);
    }
  }

  // epilogue: h2[n][p][oc] = relu(acc + bias2)
#pragma unroll
  for (int m = 0; m < 8; ++m) {
    const int ocb = m * 16 + kb * 4;  // D row = kb*4 + r
    float bz0 = bias2[ocb + 0], bz1 = bias2[ocb + 1];
    float bz2 = bias2[ocb + 2], bz3 = bias2[ocb + 3];
#pragma unroll
    for (int g = 0; g < 4; ++g) {
      const int p = p0w + g * 16 + l15;
      bf16x4 hv;
      hv[0] = (__bf16)fmaxf(acc[m][g][0] + bz0, 0.f);
      hv[1] = (__bf16)fmaxf(acc[m][g][1] + bz1, 0.f);
      hv[2] = (__bf16)fmaxf(acc[m][g][2] + bz2, 0.f);
      hv[3] = (__bf16)fmaxf(acc[m][g][3] + bz3, 0.f);
      *(bf16x4*)(h2 + ((size_t)n * 1024 + p) * 128 + ocb) = hv;
    }
  }
}

// ---------------- kernel 3: 3x3 conv (pad 1) h2 -> out[:, 512:544] ----------------
// grid: 512 blocks, 4 waves, wave = 32 oc x 64 px
__global__ void __launch_bounds__(256) conv2_kernel(
    const unsigned short* __restrict__ h2, const unsigned short* __restrict__ w2b,
    float* __restrict__ out) {
  const int t = threadIdx.x;
  const int lane = t & 63;
  const int wv = t >> 6;
  const int n = blockIdx.x >> 2;
  const int pbase = (blockIdx.x & 3) * 256 + wv * 64;
  const int l15 = lane & 15;
  const int kb = lane >> 4;

  f32x4 acc[2][4];
#pragma unroll
  for (int m = 0; m < 2; ++m)
#pragma unroll
    for (int g = 0; g < 4; ++g) acc[m][g] = (f32x4){0.f, 0.f, 0.f, 0.f};

  const unsigned short* __restrict__ h2n = h2 + (size_t)n * 1024 * 128;

#pragma unroll
  for (int tap = 0; tap < 9; ++tap) {
    const int dy = tap / 3 - 1;
    const int dx = tap % 3 - 1;
#pragma unroll
    for (int c0 = 0; c0 < 128; c0 += 32) {
      const int cb = c0 + kb * 8;
      bf16x8 af[2];
#pragma unroll
      for (int m = 0; m < 2; ++m)
        af[m] = *(const bf16x8*)(w2b + (size_t)(m * 16 + l15) * 1152 + tap * 128 + cb);
#pragma unroll
      for (int g = 0; g < 4; ++g) {
        const int p = pbase + g * 16 + l15;
        const int y = (p >> 5) & 31;
        const int xx = p & 31;
        const int y2 = y + dy;
        const int x2 = xx + dx;
        bf16x8 bv = __builtin_bit_cast(bf16x8, (ushort8){0, 0, 0, 0, 0, 0, 0, 0});
        if (y2 >= 0 && y2 < 32 && x2 >= 0 && x2 < 32)
          bv = *(const bf16x8*)(h2n + ((size_t)(y2 * 32 + x2)) * 128 + cb);
#pragma unroll
        for (int m = 0; m < 2; ++m)
          acc[m][g] = __builtin_amdgcn_mfma_f32_16x16x32_bf16(af[m], bv, acc[m][g], 0, 0, 0);
      }
    }
  }

#pragma unroll
  for (int m = 0; m < 2; ++m) {
    const int oc = m * 16 + kb * 4;
#pragma unroll
    for (int g = 0; g < 4; ++g) {
      const int p = pbase + g * 16 + l15;
#pragma unroll
      for (int r = 0; r < 4; ++r)
        __builtin_nontemporal_store(
            acc[m][g][r], &out[((size_t)n * 544 + 512 + oc + r) * 1024 + p]);
    }
  }
}

extern "C" void kernel_launch(void* const* d_in, const int* in_sizes, int n_in,
                              void* d_out, int out_size, void* d_ws, size_t ws_size,
                              hipStream_t stream) {
  const float* x = (const float*)d_in[0];
  const float* gamma1 = (const float*)d_in[1];
  const float* beta1 = (const float*)d_in[2];
  const float* w1 = (const float*)d_in[3];
  const float* gamma2 = (const float*)d_in[4];
  const float* beta2 = (const float*)d_in[5];
  const float* mean2 = (const float*)d_in[6];
  const float* var2 = (const float*)d_in[7];
  const float* w2 = (const float*)d_in[8];
  float* out = (float*)d_out;

  char* ws = (char*)d_ws;
  unsigned short* h2 = (unsigned short*)ws;
  unsigned short* w1b = (unsigned short*)(ws + 33554432);
  unsigned short* w2b = (unsigned short*)(ws + 33685504);
  float* s1 = (float*)(ws + 33759232);
  float* b1 = (float*)(ws + 33761280);
  float* bias2 = (float*)(ws + 33763328);
  float* psum = (float*)(ws + 33763840);
  float* psq = (float*)(ws + 33780224);

  prep_kernel<<<401, 256, 0, stream>>>(w1, gamma2, beta2, mean2, var2, w2, w1b, w2b, bias2);
  stats_copy_kernel<<<4096, 256, 0, stream>>>(x, out, psum, psq);
  reduce_kernel<<<2, 256, 0, stream>>>(psum, psq, gamma1, beta1, s1, b1);
  conv1_kernel<<<512, 256, 0, stream>>>(x, w1b, s1, b1, bias2, h2);
  conv2_kernel<<<512, 256, 0, stream>>>(h2, w2b, out);
}

// Round 4
// 200.407 us; speedup vs baseline: 1.1125x; 1.0337x over previous
//
#include <hip/hip_runtime.h>

#define EPS 1e-5f

typedef __bf16 bf16x8 __attribute__((ext_vector_type(8)));
typedef __bf16 bf16x4 __attribute__((ext_vector_type(4)));
typedef unsigned short ushort8 __attribute__((ext_vector_type(8)));
typedef float f32x4 __attribute__((ext_vector_type(4)));

static __device__ __forceinline__ unsigned short f2bf(float f) {
  unsigned int u = __float_as_uint(f);
  u += 0x7fffu + ((u >> 16) & 1u);
  return (unsigned short)(u >> 16);
}

// ---------------- ws layout (bytes) ----------------
// h2   (bf16, NHWC [128][1024][128])             : 0 .. 33554432
// xbf  (bf16, NCHW [128][512][1024])             : 33554432 .. 167772160
// w1b  (bf16, [128 oc][512 c], bn2-scale folded) : 167772160 .. +131072
// w2b  (bf16, [32 oc][9 tap][128 c])             : 167903232 .. +73728
// bias2(f32 [128])                               : 167976960 .. +512
// psum (f32 [512*8])                             : 167977472 .. +16384
// psq  (f32 [512*8])                             : 167993856 .. +16384

// ---- kernel 1: fused {bn1 partial stats + concat-copy + bf16 shadow of x} + prep ----
// blocks 0..4095: (nq,c) stats/copy; blocks 4096..4511: weight prep.
// x reads and out writes are nontemporal so xbf owns L3.
__global__ void __launch_bounds__(256) k1_kernel(
    const float* __restrict__ x, float* __restrict__ out,
    unsigned short* __restrict__ xbf,
    float* __restrict__ psum, float* __restrict__ psq,
    const float* __restrict__ w1, const float* __restrict__ gamma2,
    const float* __restrict__ beta2, const float* __restrict__ mean2,
    const float* __restrict__ var2, const float* __restrict__ w2,
    unsigned short* __restrict__ w1b, unsigned short* __restrict__ w2b,
    float* __restrict__ bias2) {
  const int t = threadIdx.x;
  if (blockIdx.x >= 4096) {
    int idx = (blockIdx.x - 4096) * 256 + t;
    if (idx < 128 * 512) {
      int oc = idx >> 9;
      float s2 = gamma2[oc] * rsqrtf(var2[oc] + EPS);
      w1b[idx] = f2bf(w1[idx] * s2);
    } else if (idx < 128 * 512 + 32 * 1152) {
      int i2 = idx - 128 * 512;
      int oc = i2 / 1152;
      int rem = i2 - oc * 1152;
      int tap = rem >> 7;
      int c = rem & 127;
      w2b[i2] = f2bf(w2[(oc * 128 + c) * 9 + tap]);
    } else if (idx < 128 * 512 + 32 * 1152 + 128) {
      int oc = idx - (128 * 512 + 32 * 1152);
      float s2 = gamma2[oc] * rsqrtf(var2[oc] + EPS);
      bias2[oc] = beta2[oc] - mean2[oc] * s2;
    }
    return;
  }
  const int c = blockIdx.x & 511;
  const int nq = blockIdx.x >> 9;
  float sum = 0.f, sq = 0.f;
  const f32x4* __restrict__ x4 = (const f32x4*)x;
  f32x4* out4 = (f32x4*)out;
#pragma unroll 4
  for (int i = 0; i < 16; ++i) {
    const int n = nq * 16 + i;
    f32x4 v = __builtin_nontemporal_load(&x4[(((size_t)n * 512 + c) << 8) + t]);
    __builtin_nontemporal_store(v, &out4[(((size_t)n * 544 + c) << 8) + t]);
    bf16x4 bv;
    bv[0] = (__bf16)v[0]; bv[1] = (__bf16)v[1];
    bv[2] = (__bf16)v[2]; bv[3] = (__bf16)v[3];
    *(bf16x4*)(xbf + (((size_t)n * 512 + c) << 10) + t * 4) = bv;
    sum += v[0] + v[1] + v[2] + v[3];
    sq += v[0] * v[0] + v[1] * v[1] + v[2] * v[2] + v[3] * v[3];
  }
  __shared__ float ls[2][4];
  for (int off = 32; off > 0; off >>= 1) {
    sum += __shfl_down(sum, off);
    sq += __shfl_down(sq, off);
  }
  const int w = t >> 6;
  if ((t & 63) == 0) { ls[0][w] = sum; ls[1][w] = sq; }
  __syncthreads();
  if (t == 0) {
    psum[c * 8 + nq] = ls[0][0] + ls[0][1] + ls[0][2] + ls[0][3];
    psq[c * 8 + nq] = ls[1][0] + ls[1][1] + ls[1][2] + ls[1][3];
  }
}

// ---- kernel 2: bn1+relu -> 1x1 conv -> bn2+relu -> h2 (bf16 NHWC), from xbf ----
// per-block prologue recomputes s1/b1 from psum/psq (deterministic, L2-hit).
// grid: 512 blocks (128 n * 4 quarters), 4 waves, wave = 128 oc x 64 px.
// n DESCENDING: consume freshest xbf L3 lines first.
__global__ void __launch_bounds__(256, 2) conv1_kernel(
    const unsigned short* __restrict__ xbf, const unsigned short* __restrict__ w1b,
    const float* __restrict__ psum, const float* __restrict__ psq,
    const float* __restrict__ g1, const float* __restrict__ be1,
    const float* __restrict__ bias2, unsigned short* __restrict__ h2) {
  const int t = threadIdx.x;
  __shared__ float s1s[512], b1s[512];
  for (int cc = t; cc < 512; cc += 256) {
    float S = 0.f, Q = 0.f;
#pragma unroll
    for (int q = 0; q < 8; ++q) { S += psum[cc * 8 + q]; Q += psq[cc * 8 + q]; }
    float mean = S * (1.0f / 131072.0f);
    float var = Q * (1.0f / 131072.0f) - mean * mean;
    float s = g1[cc] * rsqrtf(var + EPS);
    s1s[cc] = s;
    b1s[cc] = be1[cc] - mean * s;
  }
  __syncthreads();

  const int lane = t & 63;
  const int wv = t >> 6;
  const int n = 127 - (blockIdx.x >> 2);
  const int p0w = (blockIdx.x & 3) * 256 + wv * 64;
  const int l15 = lane & 15;
  const int kb = lane >> 4;  // 0..3

  f32x4 acc[8][4];
#pragma unroll
  for (int m = 0; m < 8; ++m)
#pragma unroll
    for (int g = 0; g < 4; ++g) acc[m][g] = (f32x4){0.f, 0.f, 0.f, 0.f};

  const unsigned short* __restrict__ xn = xbf + (size_t)n * 512 * 1024;

  for (int c0 = 0; c0 < 512; c0 += 32) {
    const int cbase = c0 + kb * 8;
    float s1v[8], b1v[8];
#pragma unroll
    for (int j = 0; j < 8; ++j) {
      s1v[j] = s1s[cbase + j];
      b1v[j] = b1s[cbase + j];
    }
    bf16x8 bf[4];
#pragma unroll
    for (int g = 0; g < 4; ++g) {
      const int p = p0w + g * 16 + l15;
      bf16x8 tmp;
#pragma unroll
      for (int j = 0; j < 8; ++j) {
        float xv = (float)*(const __bf16*)(xn + ((size_t)(cbase + j) << 10) + p);
        float a = fmaxf(fmaf(xv, s1v[j], b1v[j]), 0.f);
        tmp[j] = (__bf16)a;
      }
      bf[g] = tmp;
    }
#pragma unroll
    for (int m = 0; m < 8; ++m) {
      bf16x8 af = *(const bf16x8*)(w1b + (size_t)(m * 16 + l15) * 512 + cbase);
#pragma unroll
      for (int g = 0; g < 4; ++g)
        acc[m][g] = __builtin_amdgcn_mfma_f32_16x16x32_bf16(af, bf[g], acc[m][g], 0, 0, 0);
    }
  }

  // epilogue: h2[n][p][oc] = relu(acc + bias2)
#pragma unroll
  for (int m = 0; m < 8; ++m) {
    const int ocb = m * 16 + kb * 4;  // D row = kb*4 + r
    float bz0 = bias2[ocb + 0], bz1 = bias2[ocb + 1];
    float bz2 = bias2[ocb + 2], bz3 = bias2[ocb + 3];
#pragma unroll
    for (int g = 0; g < 4; ++g) {
      const int p = p0w + g * 16 + l15;
      bf16x4 hv;
      hv[0] = (__bf16)fmaxf(acc[m][g][0] + bz0, 0.f);
      hv[1] = (__bf16)fmaxf(acc[m][g][1] + bz1, 0.f);
      hv[2] = (__bf16)fmaxf(acc[m][g][2] + bz2, 0.f);
      hv[3] = (__bf16)fmaxf(acc[m][g][3] + bz3, 0.f);
      *(bf16x4*)(h2 + ((size_t)n * 1024 + p) * 128 + ocb) = hv;
    }
  }
}

// ---------------- kernel 3: 3x3 conv (pad 1) h2 -> out[:, 512:544] ----------------
// grid: 512 blocks, 4 waves, wave = 32 oc x 64 px
__global__ void __launch_bounds__(256) conv2_kernel(
    const unsigned short* __restrict__ h2, const unsigned short* __restrict__ w2b,
    float* __restrict__ out) {
  const int t = threadIdx.x;
  const int lane = t & 63;
  const int wv = t >> 6;
  const int n = blockIdx.x >> 2;
  const int pbase = (blockIdx.x & 3) * 256 + wv * 64;
  const int l15 = lane & 15;
  const int kb = lane >> 4;

  f32x4 acc[2][4];
#pragma unroll
  for (int m = 0; m < 2; ++m)
#pragma unroll
    for (int g = 0; g < 4; ++g) acc[m][g] = (f32x4){0.f, 0.f, 0.f, 0.f};

  const unsigned short* __restrict__ h2n = h2 + (size_t)n * 1024 * 128;

#pragma unroll
  for (int tap = 0; tap < 9; ++tap) {
    const int dy = tap / 3 - 1;
    const int dx = tap % 3 - 1;
#pragma unroll
    for (int c0 = 0; c0 < 128; c0 += 32) {
      const int cb = c0 + kb * 8;
      bf16x8 af[2];
#pragma unroll
      for (int m = 0; m < 2; ++m)
        af[m] = *(const bf16x8*)(w2b + (size_t)(m * 16 + l15) * 1152 + tap * 128 + cb);
#pragma unroll
      for (int g = 0; g < 4; ++g) {
        const int p = pbase + g * 16 + l15;
        const int y = (p >> 5) & 31;
        const int xx = p & 31;
        const int y2 = y + dy;
        const int x2 = xx + dx;
        bf16x8 bv = __builtin_bit_cast(bf16x8, (ushort8){0, 0, 0, 0, 0, 0, 0, 0});
        if (y2 >= 0 && y2 < 32 && x2 >= 0 && x2 < 32)
          bv = *(const bf16x8*)(h2n + ((size_t)(y2 * 32 + x2)) * 128 + cb);
#pragma unroll
        for (int m = 0; m < 2; ++m)
          acc[m][g] = __builtin_amdgcn_mfma_f32_16x16x32_bf16(af[m], bv, acc[m][g], 0, 0, 0);
      }
    }
  }

#pragma unroll
  for (int m = 0; m < 2; ++m) {
    const int oc = m * 16 + kb * 4;
#pragma unroll
    for (int g = 0; g < 4; ++g) {
      const int p = pbase + g * 16 + l15;
#pragma unroll
      for (int r = 0; r < 4; ++r)
        __builtin_nontemporal_store(
            acc[m][g][r], &out[((size_t)n * 544 + 512 + oc + r) * 1024 + p]);
    }
  }
}

extern "C" void kernel_launch(void* const* d_in, const int* in_sizes, int n_in,
                              void* d_out, int out_size, void* d_ws, size_t ws_size,
                              hipStream_t stream) {
  const float* x = (const float*)d_in[0];
  const float* gamma1 = (const float*)d_in[1];
  const float* beta1 = (const float*)d_in[2];
  const float* w1 = (const float*)d_in[3];
  const float* gamma2 = (const float*)d_in[4];
  const float* beta2 = (const float*)d_in[5];
  const float* mean2 = (const float*)d_in[6];
  const float* var2 = (const float*)d_in[7];
  const float* w2 = (const float*)d_in[8];
  float* out = (float*)d_out;

  char* ws = (char*)d_ws;
  unsigned short* h2 = (unsigned short*)ws;
  unsigned short* xbf = (unsigned short*)(ws + 33554432);
  unsigned short* w1b = (unsigned short*)(ws + 167772160);
  unsigned short* w2b = (unsigned short*)(ws + 167903232);
  float* bias2 = (float*)(ws + 167976960);
  float* psum = (float*)(ws + 167977472);
  float* psq = (float*)(ws + 167993856);

  k1_kernel<<<4512, 256, 0, stream>>>(x, out, xbf, psum, psq,
                                      w1, gamma2, beta2, mean2, var2, w2,
                                      w1b, w2b, bias2);
  conv1_kernel<<<512, 256, 0, stream>>>(xbf, w1b, psum, psq, gamma1, beta1, bias2, h2);
  conv2_kernel<<<512, 256, 0, stream>>>(h2, w2b, out);
}